// Round 5
// baseline (4959.230 us; speedup 1.0000x reference)
//
#include <hip/hip_runtime.h>
#include <hip/hip_bf16.h>
#include <hip/hip_cooperative_groups.h>

namespace cg = cooperative_groups;

#define T_STEPS 64
#define B_DIM 2048
#define U_DIM 1024

// ---- persistent (cooperative) config ----
#define PBM 512          // batch rows per block (4 b-slices)
#define PBU 16           // u-cols per block (64 u-blocks), f & c halves
#define PKITERS 32       // K chunks of 32

// ---- fallback (R3) config ----
#define BM 128
#define BU 64
#define BK 64
#define KITERS (U_DIM / BK)

typedef __attribute__((ext_vector_type(8))) _Float16 h8;
typedef __attribute__((ext_vector_type(4))) float f4;

__device__ __forceinline__ void async_cp16(const _Float16* g, _Float16* l) {
    __builtin_amdgcn_global_load_lds((const __attribute__((address_space(1))) void*)g,
                                     (__attribute__((address_space(3))) void*)l,
                                     16, 0, 0);
}

// ---------------- init kernels ----------------

// R: [U][2U] f32 row-major -> Rt: [2U][U] f16 (B^T layout)
__global__ void transpose_R(const float* __restrict__ R, _Float16* __restrict__ Rt) {
    __shared__ float tile[32][33];
    int nb = blockIdx.x * 32;
    int kb = blockIdx.y * 32;
    int tx = threadIdx.x, ty = threadIdx.y;   // block (32,8)
    #pragma unroll
    for (int i = ty; i < 32; i += 8)
        tile[i][tx] = R[(size_t)(kb + i) * (2 * U_DIM) + nb + tx];
    __syncthreads();
    #pragma unroll
    for (int i = ty; i < 32; i += 8)
        Rt[(size_t)(nb + i) * U_DIM + kb + tx] = (_Float16)tile[tx][i];
}

__global__ void init_state(const float* __restrict__ c0, _Float16* __restrict__ h0,
                           float* __restrict__ y) {
    int i = blockIdx.x * 256 + threadIdx.x;
    h0[i] = (_Float16)c0[i];
    if (i < 3 * B_DIM) y[i] = 0.f;
}

__global__ void init_fb(const float* __restrict__ x1_0, const float* __restrict__ x2_0,
                        float* __restrict__ x1w, float* __restrict__ x2w) {
    int i = blockIdx.x * 256 + threadIdx.x;
    x1w[i] = x1_0[i];
    x2w[i] = x2_0[i];
}

// ---------------- persistent cooperative kernel (64 KiB LDS) ----------------
__global__ __launch_bounds__(256, 1) void persistent_cell(
    _Float16* __restrict__ h0p, _Float16* __restrict__ h1p,
    const _Float16* __restrict__ Rt,
    const float* __restrict__ inputs,
    const float* __restrict__ x1_0, const float* __restrict__ x2_0,
    const float* __restrict__ kern, const float* __restrict__ bias,
    const float* __restrict__ okern,
    float* __restrict__ y,           // [3][B] rotating, pre-zeroed
    float* __restrict__ out)
{
    __shared__ __align__(16) _Float16 lB[2][PBU * U_DIM];   // 64 KiB exactly

    const int tid    = threadIdx.x;
    const int wid    = tid >> 6;
    const int lane   = tid & 63;
    const int lane15 = lane & 15;
    const int quad   = lane >> 4;
    const int blk    = blockIdx.x;
    const int xcd    = blk & 7;                    // heuristic XCD id
    const int bslice = xcd & 3;
    const int ublk   = (blk >> 3) + ((xcd >> 2) << 5);   // 0..63
    const int b0     = bslice * PBM;
    const int u0     = ublk * PBU;

    // ---- persistent B tiles (Rf/Rc u-slices), XOR-swizzled chunks ----
    #pragma unroll
    for (int i = 0; i < 16; ++i) {
        const int idx  = i * 256 + tid;      // 0..4095
        const int c    = idx & 127;
        const int r    = (idx >> 7) & 15;
        const int half = idx >> 11;
        const h8 v = *(const h8*)&Rt[(size_t)(half * U_DIM + u0 + r) * U_DIM + c * 8];
        *(h8*)&lB[half][r * 1024 + ((c ^ (r & 7)) * 8)] = v;
    }

    const int u   = u0 + lane15;
    const float kf  = kern[u];
    const float kc  = kern[U_DIM + u];
    const float bfv = bias[u];
    const float bcv = bias[U_DIM + u];
    const float okr = okern[u];

    // x1/x2 register state: thread owns rows b0 + wid*128 + mt*16 + quad*4 + reg
    float x1r[8][4], x2r[8][4];
    #pragma unroll
    for (int mt = 0; mt < 8; ++mt)
        #pragma unroll
        for (int reg = 0; reg < 4; ++reg) {
            const int b = b0 + wid * 128 + mt * 16 + quad * 4 + reg;
            x1r[mt][reg] = x1_0[b];
            x2r[mt][reg] = x2_0[b];
        }

    __syncthreads();   // lB ready

    _Float16* ha = h0p;
    _Float16* hb = h1p;
    cg::grid_group grid = cg::this_grid();
    const int xb = lane15 & 7;
    const size_t arow = (size_t)(b0 + wid * 128 + lane15);   // A row base (mt=0)

    for (int t = 0; t < T_STEPS; ++t) {
        f4 accF[8], accC[8];
        #pragma unroll
        for (int mt = 0; mt < 8; ++mt) {
            accF[mt] = (f4){0.f, 0.f, 0.f, 0.f};
            accC[mt] = (f4){0.f, 0.f, 0.f, 0.f};
        }

        // ---- barrier-free K-loop: A direct-to-VGPR, B persistent in LDS ----
        h8 acur[8], anxt[8];
        #pragma unroll
        for (int mt = 0; mt < 8; ++mt)
            acur[mt] = *(const h8*)&ha[(arow + (size_t)mt * 16) * U_DIM + quad * 8];

        #pragma unroll 2
        for (int kt = 0; kt < PKITERS; ++kt) {
            if (kt + 1 < PKITERS) {
                const size_t k0 = (size_t)(kt + 1) * 32 + quad * 8;
                #pragma unroll
                for (int mt = 0; mt < 8; ++mt)
                    anxt[mt] = *(const h8*)&ha[(arow + (size_t)mt * 16) * U_DIM + k0];
            }
            const int cs = ((kt * 4 + quad) ^ xb) * 8;
            const h8 bf = *(const h8*)&lB[0][lane15 * 1024 + cs];
            const h8 bc = *(const h8*)&lB[1][lane15 * 1024 + cs];
            #pragma unroll
            for (int mt = 0; mt < 8; ++mt) {
                accF[mt] = __builtin_amdgcn_mfma_f32_16x16x32_f16(acur[mt], bf, accF[mt], 0, 0, 0);
                accC[mt] = __builtin_amdgcn_mfma_f32_16x16x32_f16(acur[mt], bc, accC[mt], 0, 0, 0);
            }
            #pragma unroll
            for (int mt = 0; mt < 8; ++mt) acur[mt] = anxt[mt];
        }

        // ---- epilogue: gates, write h(t+1), partial y ----
        float* ycur = y + (t % 3) * B_DIM;
        #pragma unroll
        for (int mt = 0; mt < 8; ++mt) {
            const int b_base = b0 + wid * 128 + mt * 16 + quad * 4;
            float psum[4];
            #pragma unroll
            for (int reg = 0; reg < 4; ++reg) {
                const int b = b_base + reg;
                const float xf = accF[mt][reg] + x1r[mt][reg] * kf + bfv;
                const float xc = accC[mt][reg] + x1r[mt][reg] * kc + bcv;
                const float fg = 1.f / (1.f + __expf(-xf));
                const float th = 1.f - 2.f / (1.f + __expf(2.f * xc));
                const float hv = (float)ha[(size_t)b * U_DIM + u];
                const float cv = fg * hv + (1.f - fg) * th;
                hb[(size_t)b * U_DIM + u] = (_Float16)cv;
                psum[reg] = cv * okr;
            }
            #pragma unroll
            for (int reg = 0; reg < 4; ++reg) {
                float s = psum[reg];
                s += __shfl_xor(s, 1);
                s += __shfl_xor(s, 2);
                s += __shfl_xor(s, 4);
                s += __shfl_xor(s, 8);
                if (lane15 == 0) atomicAdd(&ycur[b_base + reg], s);
            }
        }

        grid.sync();   // y complete + h(t+1) visible device-wide

        // ---- update phase (register state; broadcast loads) ----
        #pragma unroll
        for (int mt = 0; mt < 8; ++mt)
            #pragma unroll
            for (int reg = 0; reg < 4; ++reg) {
                const int b = b0 + wid * 128 + mt * 16 + quad * 4 + reg;
                const float yv  = __hip_atomic_load(&ycur[b], __ATOMIC_RELAXED, __HIP_MEMORY_SCOPE_AGENT);
                const float inp = inputs[(size_t)t * B_DIM + b];
                const float x1n = x1r[mt][reg] + x2r[mt][reg];
                x2r[mt][reg] += inp * yv;
                x1r[mt][reg] = x1n;
                if (ublk == 0 && lane15 == 0)
                    out[(size_t)t * B_DIM + b] = x1n;
            }
        if (ublk == 0) {   // zero the buffer for step t+2 (device-scope stores)
            float* yz = y + ((t + 2) % 3) * B_DIM;
            __hip_atomic_store(&yz[b0 + tid],       0.f, __ATOMIC_RELAXED, __HIP_MEMORY_SCOPE_AGENT);
            __hip_atomic_store(&yz[b0 + 256 + tid], 0.f, __ATOMIC_RELAXED, __HIP_MEMORY_SCOPE_AGENT);
        }

        _Float16* tmp = ha; ha = hb; hb = tmp;
    }
}

// ---------------- fallback: R3 per-step GEMM (proven) ----------------
__global__ __launch_bounds__(256) void gemm_step(
    const _Float16* __restrict__ hA, _Float16* __restrict__ hB,
    const _Float16* __restrict__ Rt,
    const float* __restrict__ x1w, const float* __restrict__ kern,
    const float* __restrict__ bias, const float* __restrict__ okern,
    float* __restrict__ y)
{
    __shared__ __align__(16) _Float16 lA [2][BM * BK];
    __shared__ __align__(16) _Float16 lBf[2][BU * BK];
    __shared__ __align__(16) _Float16 lBc[2][BU * BK];

    const int tid    = threadIdx.x;
    const int wid    = tid >> 6;
    const int lane   = tid & 63;
    const int lane15 = lane & 15;
    const int quad   = lane >> 4;
    const int u0     = blockIdx.x * BU;
    const int b0     = blockIdx.y * BM;
    const int wrow   = (wid >> 1) * 64;
    const int wcol   = (wid & 1) * 32;

    const int srow8 = lane >> 3;
    const int skc   = (lane & 7) ^ srow8;

    f4 accF[4][2], accC[4][2];
    #pragma unroll
    for (int mt = 0; mt < 4; ++mt)
        #pragma unroll
        for (int nt = 0; nt < 2; ++nt) {
            accF[mt][nt] = (f4){0.f, 0.f, 0.f, 0.f};
            accC[mt][nt] = (f4){0.f, 0.f, 0.f, 0.f};
        }

    const _Float16* gA0  = hA + (size_t)(b0 + srow8) * U_DIM + skc * 8;
    const _Float16* gBf0 = Rt + (size_t)(u0 + srow8) * U_DIM + skc * 8;
    const _Float16* gBc0 = Rt + (size_t)(U_DIM + u0 + srow8) * U_DIM + skc * 8;

    auto stage = [&](int buf, int kt) {
        const int k0 = kt * BK;
        #pragma unroll
        for (int j = 0; j < 4; ++j) {
            const int r = wid * 4 + j;
            async_cp16(gA0 + (size_t)r * 8 * U_DIM + k0, &lA[buf][r * 512]);
        }
        #pragma unroll
        for (int j = 0; j < 2; ++j) {
            const int r = wid * 2 + j;
            async_cp16(gBf0 + (size_t)r * 8 * U_DIM + k0, &lBf[buf][r * 512]);
            async_cp16(gBc0 + (size_t)r * 8 * U_DIM + k0, &lBc[buf][r * 512]);
        }
    };

    stage(0, 0);
    const int axor = lane15 & 7;

    for (int kt = 0; kt < KITERS; ++kt) {
        const int cur = kt & 1;
        __builtin_amdgcn_s_waitcnt(0x0F70);
        __syncthreads();
        if (kt + 1 < KITERS) stage(1 - cur, kt + 1);

        #pragma unroll
        for (int ks = 0; ks < 2; ++ks) {
            h8 af[4], bff[2], bfc[2];
            #pragma unroll
            for (int mt = 0; mt < 4; ++mt) {
                const int row = wrow + mt * 16 + lane15;
                const int kq  = ks * 4 + quad;
                af[mt] = *(const h8*)&lA[cur][(row * 8 + (kq ^ axor)) * 8];
            }
            #pragma unroll
            for (int nt = 0; nt < 2; ++nt) {
                const int row = wcol + nt * 16 + lane15;
                const int kq  = ks * 4 + quad;
                bff[nt] = *(const h8*)&lBf[cur][(row * 8 + (kq ^ axor)) * 8];
                bfc[nt] = *(const h8*)&lBc[cur][(row * 8 + (kq ^ axor)) * 8];
            }
            #pragma unroll
            for (int mt = 0; mt < 4; ++mt)
                #pragma unroll
                for (int nt = 0; nt < 2; ++nt) {
                    accF[mt][nt] = __builtin_amdgcn_mfma_f32_16x16x32_f16(af[mt], bff[nt], accF[mt][nt], 0, 0, 0);
                    accC[mt][nt] = __builtin_amdgcn_mfma_f32_16x16x32_f16(af[mt], bfc[nt], accC[mt][nt], 0, 0, 0);
                }
        }
    }

    #pragma unroll
    for (int mt = 0; mt < 4; ++mt) {
        const int b_base = b0 + wrow + mt * 16 + quad * 4;
        float psum[4] = {0.f, 0.f, 0.f, 0.f};
        #pragma unroll
        for (int nt = 0; nt < 2; ++nt) {
            const int u = u0 + wcol + nt * 16 + lane15;
            const float kf  = kern[u];
            const float kc  = kern[U_DIM + u];
            const float bfv = bias[u];
            const float bcv = bias[U_DIM + u];
            const float ok  = okern[u];
            #pragma unroll
            for (int reg = 0; reg < 4; ++reg) {
                const int b = b_base + reg;
                const float x1 = x1w[b];
                const float xf = accF[mt][nt][reg] + x1 * kf + bfv;
                const float xc = accC[mt][nt][reg] + x1 * kc + bcv;
                const float fg = 1.f / (1.f + __expf(-xf));
                const float th = 1.f - 2.f / (1.f + __expf(2.f * xc));
                const float hv = (float)hA[(size_t)b * U_DIM + u];
                const float cv = fg * hv + (1.f - fg) * th;
                hB[(size_t)b * U_DIM + u] = (_Float16)cv;
                psum[reg] += cv * ok;
            }
        }
        #pragma unroll
        for (int reg = 0; reg < 4; ++reg) {
            float s = psum[reg];
            s += __shfl_xor(s, 1);
            s += __shfl_xor(s, 2);
            s += __shfl_xor(s, 4);
            s += __shfl_xor(s, 8);
            if (lane15 == 0) atomicAdd(&y[b_base + reg], s);
        }
    }
}

__global__ void step_update(const float* __restrict__ inp_t,
                            float* __restrict__ x1w, float* __restrict__ x2w,
                            float* __restrict__ y, float* __restrict__ out_t) {
    const int b = blockIdx.x * 256 + threadIdx.x;
    const float x1 = x1w[b];
    const float x2 = x2w[b];
    const float yv = y[b];
    const float x1n = x1 + x2;
    const float x2n = x2 + inp_t[b] * yv;
    x1w[b] = x1n;
    x2w[b] = x2n;
    out_t[b] = x1n;
    y[b] = 0.f;
}

// ---------------- host ----------------
extern "C" void kernel_launch(void* const* d_in, const int* in_sizes, int n_in,
                              void* d_out, int out_size, void* d_ws, size_t ws_size,
                              hipStream_t stream) {
    const float* inputs = (const float*)d_in[0];
    const float* x1_0   = (const float*)d_in[1];
    const float* x2_0   = (const float*)d_in[2];
    const float* c0     = (const float*)d_in[3];
    const float* kern   = (const float*)d_in[4];
    const float* rker   = (const float*)d_in[5];
    const float* bias   = (const float*)d_in[6];
    const float* okern  = (const float*)d_in[7];
    float* out = (float*)d_out;

    _Float16* Rt = (_Float16*)d_ws;
    _Float16* h0 = Rt + (size_t)2 * U_DIM * U_DIM;
    _Float16* h1 = h0 + (size_t)B_DIM * U_DIM;
    float* y   = (float*)(h1 + (size_t)B_DIM * U_DIM);   // 3*B
    float* x1w = y + 3 * B_DIM;
    float* x2w = x1w + B_DIM;

    transpose_R<<<dim3(64, 32), dim3(32, 8), 0, stream>>>(rker, Rt);
    init_state<<<dim3(B_DIM * U_DIM / 256), dim3(256), 0, stream>>>(c0, h0, y);

    _Float16* h0a = h0;
    _Float16* h1a = h1;
    const _Float16* Rtc = Rt;
    const float* inp_a = inputs;
    const float* x1a = x1_0;
    const float* x2a = x2_0;
    const float* ka  = kern;
    const float* ba  = bias;
    const float* oka = okern;
    float* ya = y;
    float* outa = out;
    void* args[] = {&h0a, &h1a, &Rtc, &inp_a, &x1a, &x2a, &ka, &ba, &oka, &ya, &outa};
    hipError_t err = hipLaunchCooperativeKernel((const void*)persistent_cell,
                                                dim3(256), dim3(256), args, 0, stream);
    if (err != hipSuccess) {
        (void)hipGetLastError();   // clear sticky error
        // fallback: proven R3 multi-launch path
        init_fb<<<dim3(B_DIM / 256), dim3(256), 0, stream>>>(x1_0, x2_0, x1w, x2w);
        _Float16* hcur = h0;
        _Float16* hnxt = h1;
        for (int t = 0; t < T_STEPS; ++t) {
            gemm_step<<<dim3(U_DIM / BU, B_DIM / BM), dim3(256), 0, stream>>>(
                hcur, hnxt, Rt, x1w, kern, bias, okern, y);
            step_update<<<dim3(B_DIM / 256), dim3(256), 0, stream>>>(
                inputs + (size_t)t * B_DIM, x1w, x2w, y, out + (size_t)t * B_DIM);
            _Float16* tmp = hcur; hcur = hnxt; hnxt = tmp;
        }
    }
}

// Round 6
// 1580.437 us; speedup vs baseline: 3.1379x; 3.1379x over previous
//
#include <hip/hip_runtime.h>
#include <hip/hip_bf16.h>

#define T_STEPS 64
#define B_DIM 2048
#define U_DIM 1024

#define BM 128
#define BU 64
#define BK 64
#define KITERS (U_DIM / BK)   // 16

typedef __attribute__((ext_vector_type(8))) _Float16 h8;
typedef __attribute__((ext_vector_type(4))) float f4;

__device__ __forceinline__ void async_cp16(const _Float16* g, _Float16* l) {
    __builtin_amdgcn_global_load_lds((const __attribute__((address_space(1))) void*)g,
                                     (__attribute__((address_space(3))) void*)l,
                                     16, 0, 0);
}

// ---------------- init kernels ----------------

// R: [U][2U] f32 row-major -> Rt: [2U][U] f16 (B^T layout)
__global__ void transpose_R(const float* __restrict__ R, _Float16* __restrict__ Rt) {
    __shared__ float tile[32][33];
    int nb = blockIdx.x * 32;
    int kb = blockIdx.y * 32;
    int tx = threadIdx.x, ty = threadIdx.y;   // block (32,8)
    #pragma unroll
    for (int i = ty; i < 32; i += 8)
        tile[i][tx] = R[(size_t)(kb + i) * (2 * U_DIM) + nb + tx];
    __syncthreads();
    #pragma unroll
    for (int i = ty; i < 32; i += 8)
        Rt[(size_t)(nb + i) * U_DIM + kb + tx] = (_Float16)tile[tx][i];
}

__global__ void init_state(const float* __restrict__ c0, _Float16* __restrict__ h0,
                           float* __restrict__ y) {
    int i = blockIdx.x * 256 + threadIdx.x;
    h0[i] = (_Float16)c0[i];
    if (i < 3 * B_DIM) y[i] = 0.f;
}

// ---------------- per-step fused kernel ----------------
// Dispatch t:
//   prologue: x1(t),x2(t) from x1w/x2w[(t+1)&1], y[(t+2)%3], inp[t-1]
//             (u0==0 blocks persist state to [t&1], write out[t-1], zero y[(t+1)%3])
//   K-loop:   3-stage async pipeline, vmcnt(8) waits (no full drain)
//   epilogue: gates via LDS h-tile, c -> LDS -> coalesced store, y atomics into y[t%3]
__global__ __launch_bounds__(256) void gemm_step(
    const _Float16* __restrict__ hA, _Float16* __restrict__ hB,
    const _Float16* __restrict__ Rt,
    const float* __restrict__ x1_0, const float* __restrict__ x2_0,
    float* __restrict__ x1w,          // [2][B]
    float* __restrict__ x2w,          // [2][B]
    const float* __restrict__ kern, const float* __restrict__ bias,
    const float* __restrict__ okern,
    float* __restrict__ y,            // [3][B]
    const float* __restrict__ inputs, // [T][B]
    float* __restrict__ out,          // [T][B]
    int t)
{
    __shared__ __align__(16) _Float16 lA [3][BM * BK];   // 48 KB
    __shared__ __align__(16) _Float16 lBf[3][BU * BK];   // 24 KB
    __shared__ __align__(16) _Float16 lBc[3][BU * BK];   // 24 KB
    __shared__ __align__(16) _Float16 lC[BM * 72];       // 18 KB (padded stride 72)
    __shared__ float x1s[BM];

    const int tid    = threadIdx.x;
    const int wid    = tid >> 6;
    const int lane   = tid & 63;
    const int lane15 = lane & 15;
    const int quad   = lane >> 4;
    const int u0     = blockIdx.x * BU;
    const int b0     = blockIdx.y * BM;
    const int wrow   = (wid >> 1) * 64;
    const int wcol   = (wid & 1) * 32;

    const int srow8 = lane >> 3;
    const int skc   = (lane & 7) ^ srow8;

    const _Float16* gA0  = hA + (size_t)(b0 + srow8) * U_DIM + skc * 8;
    const _Float16* gBf0 = Rt + (size_t)(u0 + srow8) * U_DIM + skc * 8;
    const _Float16* gBc0 = Rt + (size_t)(U_DIM + u0 + srow8) * U_DIM + skc * 8;

    auto stage = [&](int buf, int kt) {
        const int k0 = kt * BK;
        #pragma unroll
        for (int j = 0; j < 4; ++j) {
            const int r = wid * 4 + j;
            async_cp16(gA0 + (size_t)r * 8 * U_DIM + k0, &lA[buf][r * 512]);
        }
        #pragma unroll
        for (int j = 0; j < 2; ++j) {
            const int r = wid * 2 + j;
            async_cp16(gBf0 + (size_t)r * 8 * U_DIM + k0, &lBf[buf][r * 512]);
            async_cp16(gBc0 + (size_t)r * 8 * U_DIM + k0, &lBc[buf][r * 512]);
        }
    };

    stage(0, 0);
    stage(1, 1);

    // ---- prologue: integrator state for this step (redundant per u-block) ----
    if (tid < BM) {
        const int b = b0 + tid;
        float x1n, x2n;
        if (t == 0) {
            x1n = x1_0[b];
            x2n = x2_0[b];
        } else {
            const int rd = (t + 1) & 1;
            const float x1p = x1w[rd * B_DIM + b];
            const float x2p = x2w[rd * B_DIM + b];
            const float yp  = y[((t + 2) % 3) * B_DIM + b];
            const float ip  = inputs[(size_t)(t - 1) * B_DIM + b];
            x1n = x1p + x2p;
            x2n = x2p + ip * yp;
        }
        x1s[tid] = x1n;
        if (u0 == 0) {
            const int wr = t & 1;
            x1w[wr * B_DIM + b] = x1n;
            x2w[wr * B_DIM + b] = x2n;
            if (t > 0) out[(size_t)(t - 1) * B_DIM + b] = x1n;
            y[((t + 1) % 3) * B_DIM + b] = 0.f;
        }
    }

    f4 accF[4][2], accC[4][2];
    #pragma unroll
    for (int mt = 0; mt < 4; ++mt)
        #pragma unroll
        for (int nt = 0; nt < 2; ++nt) {
            accF[mt][nt] = (f4){0.f, 0.f, 0.f, 0.f};
            accC[mt][nt] = (f4){0.f, 0.f, 0.f, 0.f};
        }

    const int axor = lane15 & 7;

    // ---- 3-stage pipelined K-loop ----
    for (int kt = 0; kt < KITERS; ++kt) {
        const int cur = kt % 3;
        if (kt < KITERS - 1)
            __builtin_amdgcn_s_waitcnt(0x0F78);   // vmcnt(8): oldest stage done
        else
            __builtin_amdgcn_s_waitcnt(0x0F70);   // vmcnt(0): last stage
        __syncthreads();                          // cross-wave: stage kt visible; kt-1 reads done
        if (kt + 2 < KITERS) stage((kt + 2) % 3, kt + 2);

        #pragma unroll
        for (int ks = 0; ks < 2; ++ks) {
            h8 af[4], bff[2], bfc[2];
            #pragma unroll
            for (int mt = 0; mt < 4; ++mt) {
                const int row = wrow + mt * 16 + lane15;
                const int kq  = ks * 4 + quad;
                af[mt] = *(const h8*)&lA[cur][(row * 8 + (kq ^ axor)) * 8];
            }
            #pragma unroll
            for (int nt = 0; nt < 2; ++nt) {
                const int row = wcol + nt * 16 + lane15;
                const int kq  = ks * 4 + quad;
                bff[nt] = *(const h8*)&lBf[cur][(row * 8 + (kq ^ axor)) * 8];
                bfc[nt] = *(const h8*)&lBc[cur][(row * 8 + (kq ^ axor)) * 8];
            }
            #pragma unroll
            for (int mt = 0; mt < 4; ++mt)
                #pragma unroll
                for (int nt = 0; nt < 2; ++nt) {
                    accF[mt][nt] = __builtin_amdgcn_mfma_f32_16x16x32_f16(af[mt], bff[nt], accF[mt][nt], 0, 0, 0);
                    accC[mt][nt] = __builtin_amdgcn_mfma_f32_16x16x32_f16(af[mt], bfc[nt], accC[mt][nt], 0, 0, 0);
                }
        }
    }

    // ---- re-stage h-tile (rows b0..b0+127, cols u0..u0+63) into lA[0] ----
    __syncthreads();                 // all waves done reading stage buffers
    {
        const int kh = u0 >> 6;      // the A-stage whose K-range == this block's u-range
        const int k0 = kh * BK;
        #pragma unroll
        for (int j = 0; j < 4; ++j) {
            const int r = wid * 4 + j;
            async_cp16(gA0 + (size_t)r * 8 * U_DIM + k0, &lA[0][r * 512]);
        }
    }
    __builtin_amdgcn_s_waitcnt(0x0F70);   // vmcnt(0)
    __syncthreads();

    // ---- epilogue: gates; c -> lC; y partials ----
    float* ycur = y + (t % 3) * B_DIM;
    #pragma unroll
    for (int mt = 0; mt < 4; ++mt) {
        const int rl_base = wrow + mt * 16 + quad * 4;
        float psum[4] = {0.f, 0.f, 0.f, 0.f};
        #pragma unroll
        for (int nt = 0; nt < 2; ++nt) {
            const int ul = wcol + nt * 16 + lane15;
            const int u  = u0 + ul;
            const float kf  = kern[u];
            const float kc  = kern[U_DIM + u];
            const float bfv = bias[u];
            const float bcv = bias[U_DIM + u];
            const float ok  = okern[u];
            #pragma unroll
            for (int reg = 0; reg < 4; ++reg) {
                const int rl = rl_base + reg;
                const float x1 = x1s[rl];
                const float xf = accF[mt][nt][reg] + x1 * kf + bfv;
                const float xc = accC[mt][nt][reg] + x1 * kc + bcv;
                const float fg = 1.f / (1.f + __expf(-xf));
                const float th = 1.f - 2.f / (1.f + __expf(2.f * xc));
                // h from LDS tile: region rl>>3, slot (rl&7)*8 + ((ul>>3)^(rl&7)), elem ul&7
                const float hv = (float)lA[0][(rl >> 3) * 512 +
                                              ((rl & 7) * 8 + ((ul >> 3) ^ (rl & 7))) * 8 +
                                              (ul & 7)];
                const float cv = fg * hv + (1.f - fg) * th;
                lC[rl * 72 + ul] = (_Float16)cv;
                psum[reg] += cv * ok;
            }
        }
        #pragma unroll
        for (int reg = 0; reg < 4; ++reg) {
            float s = psum[reg];
            s += __shfl_xor(s, 1);
            s += __shfl_xor(s, 2);
            s += __shfl_xor(s, 4);
            s += __shfl_xor(s, 8);
            if (lane15 == 0) atomicAdd(&ycur[b0 + rl_base + reg], s);
        }
    }

    // ---- coalesced c write-out ----
    __syncthreads();
    #pragma unroll
    for (int j = 0; j < 4; ++j) {
        const int idx = j * 256 + tid;     // 1024 uint4 = 128 rows x 8
        const int row = idx >> 3;
        const int col = idx & 7;
        const uint4 v = *(const uint4*)&lC[row * 72 + col * 8];
        *(uint4*)&hB[(size_t)(b0 + row) * U_DIM + u0 + col * 8] = v;
    }
}

// ---------------- tail: out[T-1] = x1(T) ----------------
__global__ void finish(const float* __restrict__ x1w1, const float* __restrict__ x2w1,
                       float* __restrict__ out_last) {
    const int i = blockIdx.x * 256 + threadIdx.x;
    out_last[i] = x1w1[i] + x2w1[i];
}

// ---------------- host ----------------
extern "C" void kernel_launch(void* const* d_in, const int* in_sizes, int n_in,
                              void* d_out, int out_size, void* d_ws, size_t ws_size,
                              hipStream_t stream) {
    const float* inputs = (const float*)d_in[0];
    const float* x1_0   = (const float*)d_in[1];
    const float* x2_0   = (const float*)d_in[2];
    const float* c0     = (const float*)d_in[3];
    const float* kern   = (const float*)d_in[4];
    const float* rker   = (const float*)d_in[5];
    const float* bias   = (const float*)d_in[6];
    const float* okern  = (const float*)d_in[7];
    float* out = (float*)d_out;

    _Float16* Rt = (_Float16*)d_ws;                       // 4 MB
    _Float16* h0 = Rt + (size_t)2 * U_DIM * U_DIM;        // 4 MB
    _Float16* h1 = h0 + (size_t)B_DIM * U_DIM;            // 4 MB
    float* y   = (float*)(h1 + (size_t)B_DIM * U_DIM);    // 3*B
    float* x1w = y + 3 * B_DIM;                           // 2*B
    float* x2w = x1w + 2 * B_DIM;                         // 2*B

    transpose_R<<<dim3(64, 32), dim3(32, 8), 0, stream>>>(rker, Rt);
    init_state<<<dim3(B_DIM * U_DIM / 256), dim3(256), 0, stream>>>(c0, h0, y);

    _Float16* hcur = h0;
    _Float16* hnxt = h1;
    for (int t = 0; t < T_STEPS; ++t) {
        gemm_step<<<dim3(U_DIM / BU, B_DIM / BM), dim3(256), 0, stream>>>(
            hcur, hnxt, Rt, x1_0, x2_0, x1w, x2w, kern, bias, okern, y,
            inputs, out, t);
        _Float16* tmp = hcur; hcur = hnxt; hnxt = tmp;
    }
    finish<<<dim3(B_DIM / 256), dim3(256), 0, stream>>>(
        x1w + B_DIM, x2w + B_DIM, out + (size_t)(T_STEPS - 1) * B_DIM);
}